// Round 1
// baseline (52.894 us; speedup 1.0000x reference)
//
#include <hip/hip_runtime.h>
#include <hip/hip_bf16.h>

static constexpr int N_NODES_C = 1000;
static constexpr int T_DIM_C   = 1023;
static constexpr int IN_DIM_C  = N_NODES_C + 1 + T_DIM_C; // 2024
static constexpr int DM        = 512;
static constexpr int GATES     = 4 * DM;                  // 2048
static constexpr int KQ        = 16;

__device__ __forceinline__ float frcp(float x)  { return __builtin_amdgcn_rcpf(x); }
__device__ __forceinline__ float fsig(float x)  { return frcp(1.0f + __expf(-x)); }
__device__ __forceinline__ float ftanh(float x) { return 1.0f - 2.0f * frcp(__expf(2.0f * x) + 1.0f); }

// Transpose W_ih [GATES x IN_DIM] (row-major) -> Wt [IN_DIM x GATES] (row-major)
__global__ __launch_bounds__(256) void transpose_w(const float* __restrict__ W,
                                                   float* __restrict__ Wt) {
    __shared__ float tile[32][33];
    const int tx = threadIdx.x;  // 0..31
    const int ty = threadIdx.y;  // 0..7
    const int c0 = blockIdx.x * 32;  // column block in W (IN_DIM axis)
    const int g0 = blockIdx.y * 32;  // row block in W (GATES axis)
    #pragma unroll
    for (int i = ty; i < 32; i += 8) {
        const int c = c0 + tx;
        if (c < IN_DIM_C) tile[i][tx] = W[(size_t)(g0 + i) * IN_DIM_C + c];
    }
    __syncthreads();
    #pragma unroll
    for (int i = ty; i < 32; i += 8) {
        const int c = c0 + i;
        if (c < IN_DIM_C) Wt[(size_t)c * GATES + g0 + tx] = tile[tx][i];
    }
}

// One block (256 threads) per batch element b; each thread owns d = 2*tid, 2*tid+1.
__global__ __launch_bounds__(256) void vehemb(const int*   __restrict__ positions,
                                              const float* __restrict__ loads,
                                              const int*   __restrict__ timev,
                                              const float* __restrict__ b_ih,
                                              const float* __restrict__ b_hh,
                                              const float* __restrict__ gamma,
                                              const float* __restrict__ beta,
                                              const float* __restrict__ Wt,
                                              float*       __restrict__ out) {
    __shared__ __align__(16) float tl[3 * DM];  // time col + b_ih + b_hh, sections i,g,o
    __shared__ __align__(16) float lc[3 * DM];  // load col, sections i,g,o
    __shared__ float red[2][4][2];              // [parity][wave][{sum,sumsq}]

    const int b   = blockIdx.x;
    const int tid = threadIdx.x;

    int t = timev[b];
    t = t < 0 ? 0 : (t > T_DIM_C - 1 ? T_DIM_C - 1 : t);

    const float* wt_t = Wt + (size_t)(N_NODES_C + 1 + t) * GATES;
    const float* wt_l = Wt + (size_t)N_NODES_C * GATES;

    for (int j = tid; j < 3 * DM; j += 256) {
        const int sec  = j >> 9;
        const int d    = j & (DM - 1);
        const int gidx = d + (sec == 1 ? 2 * DM : (sec == 2 ? 3 * DM : 0)); // i,g,o sections
        tl[j] = wt_t[gidx] + b_ih[gidx] + b_hh[gidx];
        lc[j] = wt_l[gidx];
    }
    const float2 gm = *(const float2*)&gamma[2 * tid];
    const float2 bt = *(const float2*)&beta[2 * tid];
    __syncthreads();

    const int lane = tid & 63;
    const int wave = tid >> 6;

    for (int k = 0; k < KQ; ++k) {
        const int   p   = k & 1;
        const int   pos = positions[b * KQ + k];
        const float ld  = loads[b * KQ + k] * 0.01f;
        const float* wp = Wt + (size_t)pos * GATES;

        const float2 wi = *(const float2*)&wp[2 * tid];
        const float2 wg = *(const float2*)&wp[2 * DM + 2 * tid];
        const float2 wo = *(const float2*)&wp[3 * DM + 2 * tid];
        const float2 ti = *(const float2*)&tl[2 * tid];
        const float2 tg = *(const float2*)&tl[DM + 2 * tid];
        const float2 to = *(const float2*)&tl[2 * DM + 2 * tid];
        const float2 li = *(const float2*)&lc[2 * tid];
        const float2 lg = *(const float2*)&lc[DM + 2 * tid];
        const float2 lo = *(const float2*)&lc[2 * DM + 2 * tid];

        float hx, hy;
        {
            const float gi = wi.x + li.x * ld + ti.x;
            const float gg = wg.x + lg.x * ld + tg.x;
            const float go = wo.x + lo.x * ld + to.x;
            const float c  = fsig(gi) * ftanh(gg);
            hx = fsig(go) * ftanh(c);
        }
        {
            const float gi = wi.y + li.y * ld + ti.y;
            const float gg = wg.y + lg.y * ld + tg.y;
            const float go = wo.y + lo.y * ld + to.y;
            const float c  = fsig(gi) * ftanh(gg);
            hy = fsig(go) * ftanh(c);
        }

        float s = hx + hy;
        float q = hx * hx + hy * hy;
        #pragma unroll
        for (int off = 32; off > 0; off >>= 1) {
            s += __shfl_xor(s, off, 64);
            q += __shfl_xor(q, off, 64);
        }
        if (lane == 0) { red[p][wave][0] = s; red[p][wave][1] = q; }
        __syncthreads();
        s = red[p][0][0] + red[p][1][0] + red[p][2][0] + red[p][3][0];
        q = red[p][0][1] + red[p][1][1] + red[p][2][1] + red[p][3][1];

        const float mu  = s * (1.0f / DM);
        const float var = q * (1.0f / DM) - mu * mu;
        const float rs  = __builtin_amdgcn_rsqf(var + 1e-5f);

        float2 o2;
        o2.x = (hx - mu) * rs * gm.x + bt.x;
        o2.y = (hy - mu) * rs * gm.y + bt.y;
        *(float2*)&out[(size_t)(b * KQ + k) * DM + 2 * tid] = o2;
    }
}

extern "C" void kernel_launch(void* const* d_in, const int* in_sizes, int n_in,
                              void* d_out, int out_size, void* d_ws, size_t ws_size,
                              hipStream_t stream) {
    const int*   positions = (const int*)d_in[0];
    const float* loads     = (const float*)d_in[1];
    const int*   timev     = (const int*)d_in[2];
    const float* W_ih      = (const float*)d_in[3];
    const float* b_ih      = (const float*)d_in[4];
    const float* b_hh      = (const float*)d_in[5];
    const float* gamma     = (const float*)d_in[6];
    const float* beta      = (const float*)d_in[7];
    float*       out       = (float*)d_out;
    float*       Wt        = (float*)d_ws;  // IN_DIM_C * GATES floats = 16.6 MB

    const int B = in_sizes[2];  // 2048

    dim3 tb(32, 8);
    dim3 tg((IN_DIM_C + 31) / 32, GATES / 32);
    hipLaunchKernelGGL(transpose_w, tg, tb, 0, stream, W_ih, Wt);

    hipLaunchKernelGGL(vehemb, dim3(B), dim3(256), 0, stream,
                       positions, loads, timev, b_ih, b_hh, gamma, beta, Wt, out);
}

// Round 2
// 49.031 us; speedup vs baseline: 1.0788x; 1.0788x over previous
//
#include <hip/hip_runtime.h>
#include <hip/hip_bf16.h>

static constexpr int N_NODES_C = 1000;
static constexpr int T_DIM_C   = 1023;
static constexpr int IN_DIM_C  = N_NODES_C + 1 + T_DIM_C; // 2024
static constexpr int DM        = 512;
static constexpr int KQ        = 16;
static constexpr int ROW       = 3 * DM;                  // 1536 floats = 6 KB per Wt row

typedef float4 f4;

__device__ __forceinline__ float frcp(float x)  { return __builtin_amdgcn_rcpf(x); }
__device__ __forceinline__ float fsig(float x)  { return frcp(1.0f + __expf(-x)); }
__device__ __forceinline__ float ftanh(float x) { return 1.0f - 2.0f * frcp(__expf(2.0f * x) + 1.0f); }
__device__ __forceinline__ float hcalc(float gi, float gg, float go) {
    const float c = fsig(gi) * ftanh(gg);
    return fsig(go) * ftanh(c);
}
__device__ __forceinline__ f4 add3(f4 a, f4 b, f4 c) {
    f4 r; r.x = a.x + b.x + c.x; r.y = a.y + b.y + c.y;
    r.z = a.z + b.z + c.z; r.w = a.w + b.w + c.w; return r;
}

// W_ih [2048 x IN_DIM] -> Wt [IN_DIM x (3*512)]: sections i (rows 0..511),
// g (rows 1024..1535), o (rows 1536..2047). f-gate section is dead (c0 = 0).
__global__ __launch_bounds__(256) void transpose_w(const float* __restrict__ W,
                                                   float* __restrict__ Wt) {
    __shared__ float tile[32][33];
    const int tx = threadIdx.x;           // 0..31
    const int ty = threadIdx.y;           // 0..7
    const int c0 = blockIdx.x * 32;       // IN_DIM axis
    const int d0 = blockIdx.y * 32;       // d axis within section (0..511)
    const int s  = blockIdx.z;            // section 0,1,2
    const int gbase = (s == 0 ? 0 : (s == 1 ? 2 * DM : 3 * DM));
    #pragma unroll
    for (int i = ty; i < 32; i += 8) {
        const int c = c0 + tx;
        if (c < IN_DIM_C) tile[i][tx] = W[(size_t)(gbase + d0 + i) * IN_DIM_C + c];
    }
    __syncthreads();
    #pragma unroll
    for (int i = ty; i < 32; i += 8) {
        const int c = c0 + i;
        if (c < IN_DIM_C) Wt[(size_t)c * ROW + s * DM + d0 + tx] = tile[tx][i];
    }
}

// One wave per (b,k); each lane owns 8 consecutive d's. No LDS, no barriers.
__global__ __launch_bounds__(256, 4) void vehemb(const int*   __restrict__ positions,
                                                 const float* __restrict__ loads,
                                                 const int*   __restrict__ timev,
                                                 const float* __restrict__ b_ih,
                                                 const float* __restrict__ b_hh,
                                                 const float* __restrict__ gamma,
                                                 const float* __restrict__ beta,
                                                 const float* __restrict__ Wt,
                                                 float*       __restrict__ out) {
    const int b    = blockIdx.x;
    const int tid  = threadIdx.x;
    const int wave = tid >> 6;
    const int lane = tid & 63;
    const int d8   = lane * 8;

    int t = timev[b];
    t = t < 0 ? 0 : (t > T_DIM_C - 1 ? T_DIM_C - 1 : t);
    const float* trow = Wt + (size_t)(N_NODES_C + 1 + t) * ROW;
    const float* lrow = Wt + (size_t)N_NODES_C * ROW;

    // Registers: tl = time-col + b_ih + b_hh; lc = load-col. Layout [sec*2+half].
    f4 tl[6], lc[6];
    #pragma unroll
    for (int s = 0; s < 3; ++s) {
        const int gb = (s == 0 ? 0 : (s == 1 ? 2 * DM : 3 * DM));
        const f4 t0  = *(const f4*)&trow[s * DM + d8];
        const f4 t1  = *(const f4*)&trow[s * DM + d8 + 4];
        const f4 bi0 = *(const f4*)&b_ih[gb + d8];
        const f4 bi1 = *(const f4*)&b_ih[gb + d8 + 4];
        const f4 bh0 = *(const f4*)&b_hh[gb + d8];
        const f4 bh1 = *(const f4*)&b_hh[gb + d8 + 4];
        tl[2 * s]     = add3(t0, bi0, bh0);
        tl[2 * s + 1] = add3(t1, bi1, bh1);
        lc[2 * s]     = *(const f4*)&lrow[s * DM + d8];
        lc[2 * s + 1] = *(const f4*)&lrow[s * DM + d8 + 4];
    }
    const f4 gm0 = *(const f4*)&gamma[d8];
    const f4 gm1 = *(const f4*)&gamma[d8 + 4];
    const f4 bt0 = *(const f4*)&beta[d8];
    const f4 bt1 = *(const f4*)&beta[d8 + 4];

    // This wave's 4 (b,k) tasks: k = wave*4 + it
    int   pos[4];
    float ldv[4];
    #pragma unroll
    for (int i = 0; i < 4; ++i) {
        pos[i] = positions[b * KQ + wave * 4 + i];
        ldv[i] = loads[b * KQ + wave * 4 + i] * 0.01f;
    }

    f4 cur[6];
    {
        const float* r0 = Wt + (size_t)pos[0] * ROW + d8;
        #pragma unroll
        for (int s = 0; s < 6; ++s) cur[s] = *(const f4*)(r0 + (s >> 1) * DM + (s & 1) * 4);
    }

    #pragma unroll
    for (int it = 0; it < 4; ++it) {
        f4 nxt[6];
        if (it < 3) {
            const float* rn = Wt + (size_t)pos[it + 1] * ROW + d8;
            #pragma unroll
            for (int s = 0; s < 6; ++s) nxt[s] = *(const f4*)(rn + (s >> 1) * DM + (s & 1) * 4);
        }
        const float ld = ldv[it];
        float h[8];
        #pragma unroll
        for (int half = 0; half < 2; ++half) {
            const f4 wi = cur[0 + half], wg = cur[2 + half], wo = cur[4 + half];
            const f4 li = lc[0 + half],  lg = lc[2 + half],  lo = lc[4 + half];
            const f4 ti = tl[0 + half],  tg = tl[2 + half],  to = tl[4 + half];
            h[half * 4 + 0] = hcalc(wi.x + li.x * ld + ti.x, wg.x + lg.x * ld + tg.x, wo.x + lo.x * ld + to.x);
            h[half * 4 + 1] = hcalc(wi.y + li.y * ld + ti.y, wg.y + lg.y * ld + tg.y, wo.y + lo.y * ld + to.y);
            h[half * 4 + 2] = hcalc(wi.z + li.z * ld + ti.z, wg.z + lg.z * ld + tg.z, wo.z + lo.z * ld + to.z);
            h[half * 4 + 3] = hcalc(wi.w + li.w * ld + ti.w, wg.w + lg.w * ld + tg.w, wo.w + lo.w * ld + to.w);
        }

        float s = 0.f, q = 0.f;
        #pragma unroll
        for (int j = 0; j < 8; ++j) { s += h[j]; q += h[j] * h[j]; }
        #pragma unroll
        for (int off = 32; off > 0; off >>= 1) {
            s += __shfl_xor(s, off, 64);
            q += __shfl_xor(q, off, 64);
        }
        const float mu  = s * (1.0f / DM);
        const float var = q * (1.0f / DM) - mu * mu;
        const float rs  = __builtin_amdgcn_rsqf(var + 1e-5f);

        f4 o0, o1;
        o0.x = (h[0] - mu) * rs * gm0.x + bt0.x;
        o0.y = (h[1] - mu) * rs * gm0.y + bt0.y;
        o0.z = (h[2] - mu) * rs * gm0.z + bt0.z;
        o0.w = (h[3] - mu) * rs * gm0.w + bt0.w;
        o1.x = (h[4] - mu) * rs * gm1.x + bt1.x;
        o1.y = (h[5] - mu) * rs * gm1.y + bt1.y;
        o1.z = (h[6] - mu) * rs * gm1.z + bt1.z;
        o1.w = (h[7] - mu) * rs * gm1.w + bt1.w;
        float* op = out + (size_t)(b * KQ + wave * 4 + it) * DM + d8;
        *(f4*)op       = o0;
        *(f4*)(op + 4) = o1;

        if (it < 3) {
            #pragma unroll
            for (int s2 = 0; s2 < 6; ++s2) cur[s2] = nxt[s2];
        }
    }
}

extern "C" void kernel_launch(void* const* d_in, const int* in_sizes, int n_in,
                              void* d_out, int out_size, void* d_ws, size_t ws_size,
                              hipStream_t stream) {
    const int*   positions = (const int*)d_in[0];
    const float* loads     = (const float*)d_in[1];
    const int*   timev     = (const int*)d_in[2];
    const float* W_ih      = (const float*)d_in[3];
    const float* b_ih      = (const float*)d_in[4];
    const float* b_hh      = (const float*)d_in[5];
    const float* gamma     = (const float*)d_in[6];
    const float* beta      = (const float*)d_in[7];
    float*       out       = (float*)d_out;
    float*       Wt        = (float*)d_ws;  // IN_DIM_C * ROW floats = 12.4 MB

    const int B = in_sizes[2];  // 2048

    dim3 tb(32, 8);
    dim3 tg((IN_DIM_C + 31) / 32, DM / 32, 3);
    hipLaunchKernelGGL(transpose_w, tg, tb, 0, stream, W_ih, Wt);

    hipLaunchKernelGGL(vehemb, dim3(B), dim3(256), 0, stream,
                       positions, loads, timev, b_ih, b_hh, gamma, beta, Wt, out);
}